// Round 6
// baseline (155.194 us; speedup 1.0000x reference)
//
#include <hip/hip_runtime.h>

// Problem constants (from reference): B=256, L=512, F=128, ids in [0,1024).
#define B_   256
#define L_   512
#define F_   128
#define NID  1024
#define NTAB 513   // counts range 0..512 inclusive

// Native clang vector type (also valid for plain loads/stores).
typedef float f32x4 __attribute__((ext_vector_type(4)));

// ---------------------------------------------------------------------------
// Kernel 1 (fused prep): blocks [0,129) build the 513x128 lookup table
//   G[c][g] = b2[g] + sum_f relu(c*W1[f]+b1[f]) * W2[g][f]   (4 c's per block)
// blocks [129, 129+256) build per-batch-row histograms and emit packed counts:
//   cnts[b*L+l]       = c_src_in_src | (c_src_in_dst << 16)
//   cnts[B*L+b*L+l]   = c_dst_in_src | (c_dst_in_dst << 16)
// Masking: query id == 0 -> both counts 0 (downstream gives G[0]+G[0], which
// matches the reference's where() + encode-on-zeros).
// ---------------------------------------------------------------------------
#define TBLK 129   // ceil(513/4) table blocks

__global__ void prep_kernel(const int* __restrict__ src,
                            const int* __restrict__ dst,
                            const float* __restrict__ W1,
                            const float* __restrict__ b1,
                            const float* __restrict__ W2,
                            const float* __restrict__ b2,
                            float* __restrict__ G,
                            unsigned int* __restrict__ cnts) {
    __shared__ float h[4][F_];   // table path (2 KB)
    __shared__ int hs[NID];      // hist path  (4 KB)
    __shared__ int hd[NID];      //            (4 KB)
    const int blk = blockIdx.x;
    const int t   = threadIdx.x;  // 0..511

    if (blk < TBLK) {
        // ---- lookup-table path: c = blk*4 + (t>>7), g = t&127 ----
        const int cl = t >> 7;
        const int g  = t & 127;
        const int c  = blk * 4 + cl;
        if (c < NTAB) h[cl][g] = fmaxf(fmaf((float)c, W1[g], b1[g]), 0.0f);
        __syncthreads();
        if (c < NTAB) {
            float acc = b2[g];
            const f32x4* __restrict__ w2row = reinterpret_cast<const f32x4*>(W2 + g * F_);
            const f32x4* __restrict__ h4    = reinterpret_cast<const f32x4*>(h[cl]);
#pragma unroll
            for (int k = 0; k < F_ / 4; ++k) {
                f32x4 w  = w2row[k];   // L1/L2-resident after first block
                f32x4 hh = h4[k];      // LDS broadcast — conflict-free
                acc = fmaf(hh.x, w.x, acc);
                acc = fmaf(hh.y, w.y, acc);
                acc = fmaf(hh.z, w.z, acc);
                acc = fmaf(hh.w, w.w, acc);
            }
            G[c * F_ + g] = acc;
        }
    } else {
        // ---- histogram path: one block per batch row ----
        const int b = blk - TBLK;
        hs[t] = 0; hs[t + 512] = 0;
        hd[t] = 0; hd[t + 512] = 0;
        __syncthreads();
        const int s = src[b * L_ + t] & (NID - 1);
        const int d = dst[b * L_ + t] & (NID - 1);
        atomicAdd(&hs[s], 1);
        atomicAdd(&hd[d], 1);
        __syncthreads();
        // channel order irrelevant downstream (out = G[c0]+G[c1], symmetric)
        unsigned int cs = (s != 0) ? ((unsigned int)hs[s] | ((unsigned int)hd[s] << 16)) : 0u;
        unsigned int cd = (d != 0) ? ((unsigned int)hs[d] | ((unsigned int)hd[d] << 16)) : 0u;
        cnts[b * L_ + t] = cs;
        cnts[B_ * L_ + b * L_ + t] = cd;
    }
}

// ---------------------------------------------------------------------------
// Kernel 2: streaming gather-write.  out f32x4 #i:
//   bl = i >> 5  (index into cnts, covering [src rows | dst rows])
//   f4 = i & 31  (position along F)
// Exact-cover grid: 2048 blocks x 256 threads x UNROLL(4)-deep grid-stride
// covers total4 = 8,388,608 f32x4 in exactly 16 iterations/thread — the
// unroll keeps 4 independent load/store pairs in flight per thread.
// ---------------------------------------------------------------------------
__global__ void __launch_bounds__(256)
write_out_kernel(const float* __restrict__ G,
                 const unsigned int* __restrict__ cnts,
                 f32x4* __restrict__ out,
                 int total4) {
    const int stride = gridDim.x * blockDim.x;   // 524288: total4/stride = 16 exactly
    int i = blockIdx.x * blockDim.x + threadIdx.x;
#pragma unroll 4
    for (int it = 0; it < 16; ++it, i += stride) {
        const int f4 = i & 31;
        const int bl = i >> 5;
        const unsigned int pc = cnts[bl];   // uniform across 32 lanes -> 1 req + broadcast
        const int c0 = (int)(pc & 0xFFFFu);
        const int c1 = (int)(pc >> 16);
        f32x4 g0 = *reinterpret_cast<const f32x4*>(G + c0 * F_ + f4 * 4);
        f32x4 g1 = *reinterpret_cast<const f32x4*>(G + c1 * F_ + f4 * 4);
        out[i] = g0 + g1;                   // coalesced 16B/lane streaming store
    }
}

extern "C" void kernel_launch(void* const* d_in, const int* in_sizes, int n_in,
                              void* d_out, int out_size, void* d_ws, size_t ws_size,
                              hipStream_t stream) {
    const int*   src = (const int*)  d_in[0];   // (B, L) int32
    const int*   dst = (const int*)  d_in[1];   // (B, L) int32
    const float* W1  = (const float*)d_in[2];   // (F, 1)
    const float* b1  = (const float*)d_in[3];   // (F,)
    const float* W2  = (const float*)d_in[4];   // (F, F)
    const float* b2  = (const float*)d_in[5];   // (F,)
    float* out = (float*)d_out;                 // [src_feat | dst_feat], each (B,L,F) f32

    // Workspace: G table (513*128 f32 = 262,656 B), then packed counts (2*B*L u32).
    float* G = (float*)d_ws;
    unsigned int* cnts =
        (unsigned int*)((char*)d_ws + (size_t)NTAB * F_ * sizeof(float));

    prep_kernel<<<TBLK + B_, 512, 0, stream>>>(src, dst, W1, b1, W2, b2, G, cnts);

    const int total4 = 2 * B_ * L_ * (F_ / 4);  // 8,388,608 f32x4 = 128 MiB
    write_out_kernel<<<2048, 256, 0, stream>>>(G, cnts, (f32x4*)out, total4);
}